// Round 6
// baseline (534.028 us; speedup 1.0000x reference)
//
#include <hip/hip_runtime.h>
#include <hip/hip_bf16.h>
#include <math.h>

// ---------------------------------------------------------------------------
// LanguageModel_66477503807731: top-1 MoE FFN + tridiagonal Green's-function
// spectral features, fused. B=4,N=4096,D=512,E=4,F=2048.
// OUTPUT IS FLOAT32 (reference returns fp32; R5 debug proved the pipeline
// correct and located the failure at the out-dtype interface).
// Pipeline: transpose w1/w2 -> bf16 [e][f][d]/[e][d][f]; prep (v-proj, d,
// gate argmax routing); chunked parallel Mobius scan for Green's diag;
// grouped MFMA FFN (48-token tiles per expert) with fused spec epilogue.
// ---------------------------------------------------------------------------

typedef __bf16 bf16x8 __attribute__((ext_vector_type(8)));
typedef __bf16 bf16x4 __attribute__((ext_vector_type(4)));
typedef float  f32x4  __attribute__((ext_vector_type(4)));

#define B_   4
#define N_   4096
#define D_   512
#define E_   4
#define F_   2048
#define T_   (B_*N_)     // 16384 tokens
#define CAP_ T_          // per-expert worst-case capacity
#define BM_  48          // tokens per FFN tile (3 m-subtiles of 16)
#define TILES_ 342       // ceil(16384/48)

// Fallback-only static scratch (used iff ws_size too small; ws observed 256MB).
__device__ alignas(256) __bf16 s_w1t[(size_t)E_*F_*D_];
__device__ alignas(256) __bf16 s_w2t[(size_t)E_*D_*F_];
__device__ alignas(256) float2 s_d[T_];
__device__ alignas(256) float2 s_feats[T_];
__device__ alignas(256) float2 s_L[T_];
__device__ alignas(256) float2 s_U[T_];
__device__ alignas(256) int    s_perm[E_*CAP_];
__device__ alignas(256) int    s_cnt[E_];

// ---------------------------------------------------------------------------
// Transpose + fp32->bf16 convert:  src[e][r][c] -> dst[e][c][r]
// ---------------------------------------------------------------------------
__global__ void transpose_bf16_kernel(const float* __restrict__ src,
                                      __bf16* __restrict__ dst,
                                      int R, int C, int* cnt_zero) {
    if (cnt_zero && blockIdx.x == 0 && blockIdx.y == 0 && blockIdx.z == 0 &&
        threadIdx.x == 0 && threadIdx.y == 0) {
        #pragma unroll
        for (int e = 0; e < E_; ++e) cnt_zero[e] = 0;
    }
    __shared__ alignas(16) float tile[32][33];
    int e = blockIdx.z;
    const float* s = src + (size_t)e * R * C;
    __bf16*      d = dst + (size_t)e * R * C;
    int c0 = blockIdx.x * 32, r0 = blockIdx.y * 32;
    int tx = threadIdx.x, ty = threadIdx.y;
    #pragma unroll
    for (int i = 0; i < 4; ++i)
        tile[ty + i*8][tx] = s[(size_t)(r0 + ty + i*8) * C + c0 + tx];
    __syncthreads();
    #pragma unroll
    for (int i = 0; i < 4; ++i)
        d[(size_t)(c0 + ty + i*8) * R + r0 + tx] = (__bf16)tile[tx][ty + i*8];
}

// ---------------------------------------------------------------------------
// Prep: per token (one wave each): v-projection, d, gate argmax, routing.
// ---------------------------------------------------------------------------
__device__ inline float dot8(float4 a, float4 b, float4 c, float4 d) {
    float s =      a.x * c.x;
    s = fmaf(a.y, c.y, s); s = fmaf(a.z, c.z, s); s = fmaf(a.w, c.w, s);
    s = fmaf(b.x, d.x, s); s = fmaf(b.y, d.y, s); s = fmaf(b.z, d.z, s);
    s = fmaf(b.w, d.w, s);
    return s;
}

__device__ inline float wave_sum(float s) {
    #pragma unroll
    for (int off = 32; off > 0; off >>= 1) s += __shfl_xor(s, off);
    return s;
}

__global__ __launch_bounds__(256) void prep_kernel(
        const float* __restrict__ x,
        const float* __restrict__ vw, const float* __restrict__ vb,
        const float* __restrict__ gamma, const float* __restrict__ epsp,
        const float* __restrict__ gw, const float* __restrict__ gb,
        float2* __restrict__ dbuf, int* __restrict__ perm,
        int* __restrict__ cnt) {
    int wv = threadIdx.x >> 6, lane = threadIdx.x & 63;
    int token = blockIdx.x * 4 + wv;
    const float4* xr = (const float4*)(x + (size_t)token * D_);
    float4 xa = xr[lane*2], xb = xr[lane*2 + 1];

    const float4* vr = (const float4*)vw;
    float sv = dot8(xa, xb, vr[lane*2], vr[lane*2 + 1]);
    float sg0, sg1, sg2, sg3;
    {
        const float4* g0 = (const float4*)(gw + 0*D_);
        const float4* g1 = (const float4*)(gw + 1*D_);
        const float4* g2 = (const float4*)(gw + 2*D_);
        const float4* g3 = (const float4*)(gw + 3*D_);
        sg0 = dot8(xa, xb, g0[lane*2], g0[lane*2+1]);
        sg1 = dot8(xa, xb, g1[lane*2], g1[lane*2+1]);
        sg2 = dot8(xa, xb, g2[lane*2], g2[lane*2+1]);
        sg3 = dot8(xa, xb, g3[lane*2], g3[lane*2+1]);
    }
    sv  = wave_sum(sv);
    sg0 = wave_sum(sg0); sg1 = wave_sum(sg1);
    sg2 = wave_sum(sg2); sg3 = wave_sum(sg3);

    if (lane == 0) {
        float v = sv + vb[0];
        v = fminf(fmaxf(v, -3.0f), 3.0f);
        float eps = log1pf(expf(epsp[0])) + 1e-6f;          // softplus + 1e-6
        dbuf[token] = make_float2(v - 2.0f, -(eps + gamma[0]));

        float l0 = sg0 + gb[0], l1 = sg1 + gb[1], l2 = sg2 + gb[2], l3 = sg3 + gb[3];
        float best = l0; int be = 0;                         // first-max on tie
        if (l1 > best) { best = l1; be = 1; }
        if (l2 > best) { best = l2; be = 2; }
        if (l3 > best) { best = l3; be = 3; }
        int pos = atomicAdd(&cnt[be], 1);
        perm[be * CAP_ + pos] = token;
    }
}

// ---------------------------------------------------------------------------
// Scan: chunked parallel continued-fraction (verified vs serial to 5e-7).
// 8 scans (4 batch x fwd/bwd), 64 chunks of 64. 1 block x 512 threads.
// ---------------------------------------------------------------------------
__global__ __launch_bounds__(512) void scan_kernel(
        const float2* __restrict__ dbuf, float2* __restrict__ Lb,
        float2* __restrict__ Ub, float2* __restrict__ feats) {
    __shared__ alignas(16) float chunkM[8][64][8];
    __shared__ alignas(16) float bound[8][64][4];
    int tid = threadIdx.x;
    int s = tid >> 6, c = tid & 63;
    int b = s & 3, dir = s >> 2;

    // Phase A: per-chunk Mobius matrix product (P_0 = identity, normalized).
    {
        float ar=1, ai=0, br=0, bi=0, cr=0, ci=0, dr=1, di=0;
        for (int j = 0; j < 64; ++j) {
            int seq = c*64 + j;
            int orig = dir ? (N_-1 - seq) : seq;
            float2 dv = dbuf[b*N_ + orig];
            float nar = dv.x*ar - dv.y*ai - cr;
            float nai = dv.x*ai + dv.y*ar - ci;
            float nbr = dv.x*br - dv.y*bi - dr;
            float nbi = dv.x*bi + dv.y*br - di;
            cr = ar; ci = ai; dr = br; di = bi;
            ar = nar; ai = nai; br = nbr; bi = nbi;
            if ((j & 7) == 7) {
                float m = fmaxf(fmaxf(fmaxf(fabsf(ar),fabsf(ai)),fmaxf(fabsf(br),fabsf(bi))),
                                fmaxf(fmaxf(fabsf(cr),fabsf(ci)),fmaxf(fabsf(dr),fabsf(di))));
                float inv = 1.0f / fmaxf(m, 1e-30f);
                ar*=inv; ai*=inv; br*=inv; bi*=inv; cr*=inv; ci*=inv; dr*=inv; di*=inv;
            }
        }
        float* cm = chunkM[s][c];
        cm[0]=ar; cm[1]=ai; cm[2]=br; cm[3]=bi; cm[4]=cr; cm[5]=ci; cm[6]=dr; cm[7]=di;
    }
    __syncthreads();

    // Phase B: sequential combine of chunk matrices (8 lanes, 64 steps each).
    if (tid < 8) {
        int ss = tid;
        float pr=1, pi=0, qr=0, qi=0;                 // (p,q)=(1,0) => L_in = inf
        for (int cc = 0; cc < 64; ++cc) {
            float* bd = bound[ss][cc];
            bd[0]=pr; bd[1]=pi; bd[2]=qr; bd[3]=qi;
            const float* m = chunkM[ss][cc];
            float npr = m[0]*pr - m[1]*pi + m[2]*qr - m[3]*qi;
            float npi = m[0]*pi + m[1]*pr + m[2]*qi + m[3]*qr;
            float nqr = m[4]*pr - m[5]*pi + m[6]*qr - m[7]*qi;
            float nqi = m[4]*pi + m[5]*pr + m[6]*qi + m[7]*qr;
            float mx = fmaxf(fmaxf(fabsf(npr),fabsf(npi)), fmaxf(fabsf(nqr),fabsf(nqi)));
            float inv = 1.0f / fmaxf(mx, 1e-30f);
            pr = npr*inv; pi = npi*inv; qr = nqr*inv; qi = nqi*inv;
        }
    }
    __syncthreads();

    // Phase C: per-chunk elementwise recurrence from boundary value (q/p).
    {
        const float* bd = bound[s][c];
        float pr=bd[0], pi=bd[1], qr=bd[2], qi=bd[3];
        float den = fmaxf(pr*pr + pi*pi, 1e-30f);
        float invr = (qr*pr + qi*pi) / den;
        float invi = (qi*pr - qr*pi) / den;
        for (int j = 0; j < 64; ++j) {
            int seq = c*64 + j;
            int orig = dir ? (N_-1 - seq) : seq;
            int t = b*N_ + orig;
            float2 dv = dbuf[t];
            float Lr = dv.x - invr, Li = dv.y - invi;
            if (dir) Ub[t] = make_float2(Lr, Li);
            else     Lb[t] = make_float2(Lr, Li);
            float d2 = Lr*Lr + Li*Li;
            invr = Lr / d2; invi = -Li / d2;
        }
    }
    __threadfence();
    __syncthreads();

    // Phase D: G_ii = 1/(L+U-d), clip -> feats.
    for (int t = tid; t < T_; t += 512) {
        float2 L = Lb[t], U = Ub[t], dv = dbuf[t];
        float sr = L.x + U.x - dv.x;
        float si = L.y + U.y - dv.y;
        float den = sr*sr + si*si;
        float Gr = sr / den, Gi = -si / den;
        Gr = fminf(fmaxf(Gr, -10.0f), 10.0f);
        Gi = fminf(fmaxf(Gi, -10.0f), 10.0f);
        feats[t] = make_float2(Gr, Gi);
    }
}

// ---------------------------------------------------------------------------
// Grouped fused FFN (verified vs independent serial path to 0.014 in R5).
// Per (expert, 48-token tile): P=gelu(X@W1c+b1) in LDS, Y += P@W2c, 16
// F-chunks of 128. Epilogue: out = Y + b2 + bk*(f.re*ow0 + f.im*ow1 + ob),
// FP32 stores. 512 threads = 8 waves. LDS 62,976B.
// ---------------------------------------------------------------------------
__global__ __launch_bounds__(512) void ffn_kernel(
        const float* __restrict__ x,
        const float* __restrict__ b1, const float* __restrict__ b2,
        const float* __restrict__ outw, const float* __restrict__ outb,
        const float* __restrict__ bk,
        float* __restrict__ out,
        const __bf16* __restrict__ w1t, const __bf16* __restrict__ w2t,
        const float2* __restrict__ feats, const int* __restrict__ perm,
        const int* __restrict__ cnt_p) {
    int e    = blockIdx.x / TILES_;
    int tile = blockIdx.x % TILES_;
    int cnt  = cnt_p[e];
    if (tile * BM_ >= cnt) return;

    __shared__ alignas(16) __bf16 X[BM_][520];   // row stride 1040B = 65*16
    __shared__ alignas(16) __bf16 P[BM_][136];   // row stride 272B  = 17*16

    int tid = threadIdx.x;
    int lane = tid & 63, wv = tid >> 6;
    int fl = lane & 15, gl = lane >> 4;

    // ---- stage X tile (gathered tokens, fp32 -> bf16) ----
    if (tid < BM_ * 8) {
        int row = tid >> 3, part = tid & 7;
        int gr = tile * BM_ + row;
        int token = (gr < cnt) ? perm[e * CAP_ + gr] : -1;
        const float4* xr = (const float4*)(x + (size_t)(token < 0 ? 0 : token) * D_);
        #pragma unroll
        for (int i = 0; i < 16; ++i) {
            float4 v = make_float4(0.f, 0.f, 0.f, 0.f);
            if (token >= 0) v = xr[part * 16 + i];
            int c0 = part * 64 + i * 4;
            bf16x4 w = { (__bf16)v.x, (__bf16)v.y, (__bf16)v.z, (__bf16)v.w };
            *(bf16x4*)&X[row][c0] = w;
        }
    }
    __syncthreads();

    f32x4 yac[3][4];
    #pragma unroll
    for (int m = 0; m < 3; ++m)
        #pragma unroll
        for (int n = 0; n < 4; ++n)
            yac[m][n] = (f32x4){0.f, 0.f, 0.f, 0.f};

    for (int fc = 0; fc < 16; ++fc) {
        // ---- phase 1: P[:, 16w..16w+16) = gelu(X @ W1[:, chunk] + b1) ----
        int fcol = fc * 128 + wv * 16 + fl;
        float b1v = b1[e * F_ + fcol];
        f32x4 pac[3];
        #pragma unroll
        for (int m = 0; m < 3; ++m) pac[m] = (f32x4){0.f, 0.f, 0.f, 0.f};
        const __bf16* w1p = w1t + ((size_t)e * F_ + fcol) * D_;
        #pragma unroll
        for (int k0 = 0; k0 < 512; k0 += 32) {
            int k = k0 + gl * 8;
            bf16x8 bfrag = *(const bf16x8*)(w1p + k);
            #pragma unroll
            for (int m = 0; m < 3; ++m) {
                bf16x8 afrag = *(const bf16x8*)&X[m * 16 + fl][k];
                pac[m] = __builtin_amdgcn_mfma_f32_16x16x32_bf16(afrag, bfrag, pac[m], 0, 0, 0);
            }
        }
        #pragma unroll
        for (int m = 0; m < 3; ++m)
            #pragma unroll
            for (int r = 0; r < 4; ++r) {
                float val = pac[m][r] + b1v;
                float g = 0.5f * val * (1.0f + erff(val * 0.70710678118654752f));
                P[m * 16 + gl * 4 + r][wv * 16 + fl] = (__bf16)g;
            }
        __syncthreads();

        // ---- phase 2: Y[:, 64w..64w+64) += P @ W2[chunk, :] ----
        #pragma unroll
        for (int k2 = 0; k2 < 4; ++k2) {
            bf16x8 a2[3];
            #pragma unroll
            for (int m = 0; m < 3; ++m)
                a2[m] = *(const bf16x8*)&P[m * 16 + fl][k2 * 32 + gl * 8];
            #pragma unroll
            for (int n = 0; n < 4; ++n) {
                int dcol = wv * 64 + n * 16 + fl;
                const __bf16* w2p = w2t + ((size_t)e * D_ + dcol) * F_
                                  + fc * 128 + k2 * 32 + gl * 8;
                bf16x8 bfrag = *(const bf16x8*)w2p;
                #pragma unroll
                for (int m = 0; m < 3; ++m)
                    yac[m][n] = __builtin_amdgcn_mfma_f32_16x16x32_bf16(a2[m], bfrag, yac[m][n], 0, 0, 0);
            }
        }
        __syncthreads();
    }

    // ---- epilogue: out = Y + b2 + bk * (f0*ow0 + f1*ow1 + ob), FP32 store ----
    float c_b2[4], c_o0[4], c_o1[4], c_ob[4], c_bk[4];
    #pragma unroll
    for (int n = 0; n < 4; ++n) {
        int dcol = wv * 64 + n * 16 + fl;
        c_b2[n] = b2[e * D_ + dcol];
        c_o0[n] = outw[dcol * 2 + 0];
        c_o1[n] = outw[dcol * 2 + 1];
        c_ob[n] = outb[dcol];
        c_bk[n] = bk[dcol];
    }
    #pragma unroll
    for (int m = 0; m < 3; ++m)
        #pragma unroll
        for (int r = 0; r < 4; ++r) {
            int lr = m * 16 + gl * 4 + r;
            int gr = tile * BM_ + lr;
            if (gr >= cnt) continue;
            int token = perm[e * CAP_ + gr];
            float2 ft = feats[token];
            float* orow = out + (size_t)token * D_;
            #pragma unroll
            for (int n = 0; n < 4; ++n) {
                int dcol = wv * 64 + n * 16 + fl;
                float spec = ft.x * c_o0[n] + ft.y * c_o1[n] + c_ob[n];
                orow[dcol] = yac[m][n][r] + c_b2[n] + c_bk[n] * spec;
            }
        }
}

// ---------------------------------------------------------------------------
extern "C" void kernel_launch(void* const* d_in, const int* in_sizes, int n_in,
                              void* d_out, int out_size, void* d_ws, size_t ws_size,
                              hipStream_t stream) {
    const float* x     = (const float*)d_in[0];
    const float* vpw   = (const float*)d_in[1];
    const float* vpb   = (const float*)d_in[2];
    const float* gamma = (const float*)d_in[3];
    const float* epsp  = (const float*)d_in[4];
    const float* gw    = (const float*)d_in[5];
    const float* gb    = (const float*)d_in[6];
    const float* w1    = (const float*)d_in[7];
    const float* b1    = (const float*)d_in[8];
    const float* w2    = (const float*)d_in[9];
    const float* b2    = (const float*)d_in[10];
    const float* ow    = (const float*)d_in[11];
    const float* ob    = (const float*)d_in[12];
    const float* bk    = (const float*)d_in[13];
    float* out = (float*)d_out;    // reference output dtype is float32

    const size_t szW  = (size_t)E_ * F_ * D_ * sizeof(__bf16);   // 8 MB each
    const size_t szF2 = (size_t)T_ * sizeof(float2);             // 128 KB each
    const size_t szPm = (size_t)E_ * CAP_ * sizeof(int);         // 256 KB
    const size_t szCt = 256;
    size_t need = 2*szW + 4*szF2 + szPm + szCt + 8*256;

    __bf16 *w1t, *w2t; float2 *dbuf, *Lb, *Ub, *feats; int *perm, *cnt;
    int use_ws = (d_ws != nullptr && ws_size >= need);
    if (use_ws) {
        size_t off = 0;
        auto carve = [&](size_t bytes) {
            void* p = (char*)d_ws + off;
            off += (bytes + 255) & ~(size_t)255;
            return p;
        };
        w1t   = (__bf16*)carve(szW);
        w2t   = (__bf16*)carve(szW);
        dbuf  = (float2*)carve(szF2);
        Lb    = (float2*)carve(szF2);
        Ub    = (float2*)carve(szF2);
        feats = (float2*)carve(szF2);
        perm  = (int*)   carve(szPm);
        cnt   = (int*)   carve(szCt);
    } else {
        void* p;
        hipGetSymbolAddress(&p, HIP_SYMBOL(s_w1t));  w1t   = (__bf16*)p;
        hipGetSymbolAddress(&p, HIP_SYMBOL(s_w2t));  w2t   = (__bf16*)p;
        hipGetSymbolAddress(&p, HIP_SYMBOL(s_d));    dbuf  = (float2*)p;
        hipGetSymbolAddress(&p, HIP_SYMBOL(s_L));    Lb    = (float2*)p;
        hipGetSymbolAddress(&p, HIP_SYMBOL(s_U));    Ub    = (float2*)p;
        hipGetSymbolAddress(&p, HIP_SYMBOL(s_feats));feats = (float2*)p;
        hipGetSymbolAddress(&p, HIP_SYMBOL(s_perm)); perm  = (int*)p;
        hipGetSymbolAddress(&p, HIP_SYMBOL(s_cnt));  cnt   = (int*)p;
    }

    dim3 tb(32, 8);
    // w1[e][D][F] -> w1t[e][F][D]   (also zeroes cnt)
    transpose_bf16_kernel<<<dim3(F_/32, D_/32, E_), tb, 0, stream>>>(w1, w1t, D_, F_, cnt);
    // w2[e][F][D] -> w2t[e][D][F]
    transpose_bf16_kernel<<<dim3(D_/32, F_/32, E_), tb, 0, stream>>>(w2, w2t, F_, D_, nullptr);
    prep_kernel<<<T_/4, 256, 0, stream>>>(x, vpw, vpb, gamma, epsp, gw, gb, dbuf, perm, cnt);
    scan_kernel<<<1, 512, 0, stream>>>(dbuf, Lb, Ub, feats);
    ffn_kernel<<<E_*TILES_, 512, 0, stream>>>(x, b1, b2, ow, ob, bk, out, w1t, w2t, feats, perm, cnt);
}